// Round 5
// baseline (445.794 us; speedup 1.0000x reference)
//
#include <hip/hip_runtime.h>

#define N_NODES 100000
#define SCAN_NB 128
#define SCAN_TPB 256

typedef _Float16 half_t;
typedef __attribute__((ext_vector_type(8))) _Float16 v8h;
typedef __attribute__((ext_vector_type(4))) _Float16 v4h;
typedef __attribute__((ext_vector_type(4))) float v4f;

// ---------------- CSR build ----------------

__global__ void count_kernel(const int* __restrict__ src, const int* __restrict__ dst,
                             int* __restrict__ ocnt, int* __restrict__ icnt, int E) {
    int e = blockIdx.x * blockDim.x + threadIdx.x;
    if (e < E) {
        atomicAdd(&ocnt[src[e]], 1);
        atomicAdd(&icnt[dst[e]], 1);
    }
}

__global__ __launch_bounds__(SCAN_TPB) void scan_reduce(const int* __restrict__ cnt,
                                                        int* __restrict__ blockSum, int n) {
    __shared__ int s[SCAN_TPB];
    int chunk = (n + SCAN_NB - 1) / SCAN_NB;
    int beg = blockIdx.x * chunk;
    int end = min(beg + chunk, n);
    int sum = 0;
    for (int i = beg + threadIdx.x; i < end; i += SCAN_TPB) sum += cnt[i];
    s[threadIdx.x] = sum;
    __syncthreads();
    for (int off = SCAN_TPB / 2; off > 0; off >>= 1) {
        if (threadIdx.x < off) s[threadIdx.x] += s[threadIdx.x + off];
        __syncthreads();
    }
    if (threadIdx.x == 0) blockSum[blockIdx.x] = s[0];
}

__global__ __launch_bounds__(SCAN_NB) void scan_offsets(int* __restrict__ blockSum,
                                                        int* __restrict__ rowptr_total) {
    __shared__ int s[SCAN_NB];
    int tid = threadIdx.x;
    int v = blockSum[tid];
    s[tid] = v;
    __syncthreads();
    for (int off = 1; off < SCAN_NB; off <<= 1) {
        int t = (tid >= off) ? s[tid - off] : 0;
        __syncthreads();
        s[tid] += t;
        __syncthreads();
    }
    blockSum[tid] = s[tid] - v;
    if (tid == SCAN_NB - 1) rowptr_total[0] = s[tid];
}

__global__ __launch_bounds__(SCAN_TPB) void scan_final(const int* __restrict__ cnt,
                                                       const int* __restrict__ blockSum,
                                                       int* __restrict__ rowptr,
                                                       int* __restrict__ cursor, int n) {
    __shared__ int s[SCAN_TPB];
    int chunk = (n + SCAN_NB - 1) / SCAN_NB;
    int beg = blockIdx.x * chunk;
    int end = min(beg + chunk, n);
    int carry = blockSum[blockIdx.x];
    for (int base = beg; base < end; base += SCAN_TPB) {
        int i = base + threadIdx.x;
        int v = (i < end) ? cnt[i] : 0;
        s[threadIdx.x] = v;
        __syncthreads();
        for (int off = 1; off < SCAN_TPB; off <<= 1) {
            int t = (threadIdx.x >= off) ? s[threadIdx.x - off] : 0;
            __syncthreads();
            s[threadIdx.x] += t;
            __syncthreads();
        }
        int excl = s[threadIdx.x] - v;
        if (i < end) {
            rowptr[i] = carry + excl;
            cursor[i] = carry + excl;
        }
        int roundSum = s[SCAN_TPB - 1];
        __syncthreads();
        carry += roundSum;
    }
}

__global__ void norm_kernel(int* __restrict__ ocnt, int* __restrict__ icnt, int n) {
    int i = blockIdx.x * blockDim.x + threadIdx.x;
    if (i < n) {
        float o = (float)max(ocnt[i], 1);
        float in = (float)max(icnt[i], 1);
        ((float*)ocnt)[i] = rsqrtf(o);
        ((float*)icnt)[i] = rsqrtf(in);
    }
}

__global__ void fill_kernel(const int* __restrict__ src, const int* __restrict__ dst,
                            int* __restrict__ cursor, int* __restrict__ eidx, int E) {
    int e = blockIdx.x * blockDim.x + threadIdx.x;
    if (e < E) {
        int pos = atomicAdd(&cursor[dst[e]], 1);
        eidx[pos] = src[e];
    }
}

// ---------------- conversions ----------------

__global__ void conv_x(const float* __restrict__ x, const float* __restrict__ invOut,
                       half_t* __restrict__ xh) {
    int t = blockIdx.x * blockDim.x + threadIdx.x;  // N_NODES*32 chunks
    int n = t >> 5;
    if (n >= N_NODES) return;
    float4 v = ((const float4*)x)[t];
    float s = invOut[n];
    v4h h;
    h[0] = (half_t)(v.x * s);
    h[1] = (half_t)(v.y * s);
    h[2] = (half_t)(v.z * s);
    h[3] = (half_t)(v.w * s);
    *(v4h*)(xh + (size_t)t * 4) = h;
}

// Wt[n][k] = (half) W[k][n]
__global__ void convT_w(const float* __restrict__ W, half_t* __restrict__ Wt, int K, int N) {
    int t = blockIdx.x * blockDim.x + threadIdx.x;
    if (t >= K * N) return;
    int n = t / K;
    int k = t - n * K;
    Wt[t] = (half_t)W[(size_t)k * N + n];
}

// ---------------- fused gather + MFMA GEMM, layer 1 ----------------
// A-tile (64 rows) built by CSR gather of xh; C = relu((A@W1)*invIn + b1)*invOut, fp16.
// 4 waves, wave n-span 64 (N=256, 4 n-tiles/wave), B held in registers.

__global__ __launch_bounds__(256) void fused_l1(
    const half_t* __restrict__ xh, const int* __restrict__ rowptr,
    const int* __restrict__ eidx, const half_t* __restrict__ Wt1,
    const float* __restrict__ invIn, const float* __restrict__ invOut,
    const float* __restrict__ b1, half_t* __restrict__ h1) {
    constexpr int K = 128, N = 256, LDA = K + 8;  // 272B row: uniform 8 words/bank for b128
    __shared__ half_t As[64][LDA];
    __shared__ float iiS[64], ioS[64];
    const int tid = threadIdx.x;
    const int wave = tid >> 6, lane = tid & 63;
    const int quad = lane >> 4, l16 = lane & 15;
    const int m0 = blockIdx.x * 64;
    const int n0 = wave * 64;

    // B-fragments into registers (global loads overlap the gather phase)
    v8h b[4][4];
    float bv[4];
#pragma unroll
    for (int j = 0; j < 4; ++j) {
        int gn = n0 + j * 16 + l16;
        bv[j] = b1[gn];
#pragma unroll
        for (int kc = 0; kc < 4; ++kc)
            b[j][kc] = *(const v8h*)(Wt1 + (size_t)gn * K + kc * 32 + quad * 8);
    }
    if (tid < 64) {
        int gm = m0 + tid;
        bool ok = gm < N_NODES;
        iiS[tid] = ok ? invIn[gm] : 0.f;
        ioS[tid] = ok ? invOut[gm] : 0.f;
    }

    // gather phase: 64 rows x 16 chunks(8 halves) = 1024 tasks, 4 per thread.
    // 16 chunk-threads of a row walk the same edge list -> 256B coalesced reads.
#pragma unroll
    for (int t = 0; t < 4; ++t) {
        int task = tid + t * 256;
        int r = task >> 4, c = task & 15;
        int gm = m0 + r;
        float acc[8] = {};
        if (gm < N_NODES) {
            int beg = rowptr[gm], end = rowptr[gm + 1];
            for (int j = beg; j < end; ++j) {
                int s = eidx[j];
                v8h val = *(const v8h*)(xh + (size_t)s * K + c * 8);
#pragma unroll
                for (int q = 0; q < 8; ++q) acc[q] += (float)val[q];
            }
        }
        v8h o;
#pragma unroll
        for (int q = 0; q < 8; ++q) o[q] = (half_t)acc[q];
        *(v8h*)&As[r][c * 8] = o;
    }
    __syncthreads();

    // MFMA phase: 4 m-tiles per wave
    for (int mt = 0; mt < 4; ++mt) {
        v8h a[4];
#pragma unroll
        for (int kc = 0; kc < 4; ++kc)
            a[kc] = *(const v8h*)&As[mt * 16 + l16][kc * 32 + quad * 8];
        v4f acc[4] = {};
#pragma unroll
        for (int kc = 0; kc < 4; ++kc)
#pragma unroll
            for (int j = 0; j < 4; ++j)
                acc[j] = __builtin_amdgcn_mfma_f32_16x16x32_f16(a[kc], b[j][kc], acc[j], 0, 0, 0);
#pragma unroll
        for (int j = 0; j < 4; ++j) {
            int gn = n0 + j * 16 + l16;
#pragma unroll
            for (int r = 0; r < 4; ++r) {
                int lr = mt * 16 + quad * 4 + r;
                int gm = m0 + lr;
                if (gm < N_NODES) {
                    float z = (acc[j][r] * iiS[lr] + bv[j]) * ioS[lr];
                    h1[(size_t)gm * N + gn] = (half_t)fmaxf(z, 0.f);
                }
            }
        }
    }
}

// ---------------- GEMM2: t2 = h1 @ W2, single-stage A, B in regs ----------------
// M=1e5, K=256, N=128. 4 waves, wave n-span 32 (2 n-tiles).

__global__ __launch_bounds__(256) void gemm2_kernel(
    const half_t* __restrict__ A, const half_t* __restrict__ Wt2,
    half_t* __restrict__ C) {
    constexpr int K = 256, N = 128, LDA = K + 8;  // 528B row
    __shared__ half_t As[64][LDA];
    const int tid = threadIdx.x;
    const int wave = tid >> 6, lane = tid & 63;
    const int quad = lane >> 4, l16 = lane & 15;
    const int m0 = blockIdx.x * 64;
    const int n0 = wave * 32;

    v8h b[2][8];
#pragma unroll
    for (int j = 0; j < 2; ++j) {
        int gn = n0 + j * 16 + l16;
#pragma unroll
        for (int kc = 0; kc < 8; ++kc)
            b[j][kc] = *(const v8h*)(Wt2 + (size_t)gn * K + kc * 32 + quad * 8);
    }

    // stage A: 64 rows x 32 chunks(16B) = 2048 tasks, 8 per thread (coalesced rows)
#pragma unroll
    for (int t = 0; t < 8; ++t) {
        int task = tid + t * 256;
        int r = task >> 5, c = task & 31;
        int gm = m0 + r;
        float4 v = make_float4(0.f, 0.f, 0.f, 0.f);
        if (gm < N_NODES) v = *(const float4*)(A + (size_t)gm * K + c * 8);
        *(float4*)&As[r][c * 8] = v;
    }
    __syncthreads();

    for (int mt = 0; mt < 4; ++mt) {
        v8h a[8];
#pragma unroll
        for (int kc = 0; kc < 8; ++kc)
            a[kc] = *(const v8h*)&As[mt * 16 + l16][kc * 32 + quad * 8];
        v4f acc[2] = {};
#pragma unroll
        for (int kc = 0; kc < 8; ++kc)
#pragma unroll
            for (int j = 0; j < 2; ++j)
                acc[j] = __builtin_amdgcn_mfma_f32_16x16x32_f16(a[kc], b[j][kc], acc[j], 0, 0, 0);
#pragma unroll
        for (int j = 0; j < 2; ++j) {
            int gn = n0 + j * 16 + l16;
#pragma unroll
            for (int r = 0; r < 4; ++r) {
                int gm = m0 + mt * 16 + quad * 4 + r;
                if (gm < N_NODES) C[(size_t)gm * N + gn] = (half_t)acc[j][r];
            }
        }
    }
}

// ---------------- fused gather(+relu epi) + GEMM, layer 3 ----------------
// A-tile = h2 = relu((gather(t2))*invIn + b2)*invOut ; t3 = A @ W3 (N=40), fp16.
// 4 waves: wave handles m-tile mt=wave, 3 n-tiles (gn<40 masked).

__global__ __launch_bounds__(256) void fused_l3(
    const half_t* __restrict__ t2, const int* __restrict__ rowptr,
    const int* __restrict__ eidx, const half_t* __restrict__ Wt3,
    const float* __restrict__ invIn, const float* __restrict__ invOut,
    const float* __restrict__ b2, half_t* __restrict__ t3) {
    constexpr int K = 128, N = 40, LDA = K + 8;
    __shared__ half_t As[64][LDA];
    const int tid = threadIdx.x;
    const int wave = tid >> 6, lane = tid & 63;
    const int quad = lane >> 4, l16 = lane & 15;
    const int m0 = blockIdx.x * 64;

    v8h b[3][4];
#pragma unroll
    for (int j = 0; j < 3; ++j) {
        int gn = j * 16 + l16;
#pragma unroll
        for (int kc = 0; kc < 4; ++kc)
            b[j][kc] = (gn < N) ? *(const v8h*)(Wt3 + (size_t)gn * K + kc * 32 + quad * 8)
                                : (v8h)(half_t)0;
    }

    // gather phase with fused relu epilogue
#pragma unroll
    for (int t = 0; t < 4; ++t) {
        int task = tid + t * 256;
        int r = task >> 4, c = task & 15;
        int gm = m0 + r;
        float acc[8] = {};
        float ii = 0.f, io = 0.f;
        if (gm < N_NODES) {
            ii = invIn[gm];
            io = invOut[gm];
            int beg = rowptr[gm], end = rowptr[gm + 1];
            for (int j = beg; j < end; ++j) {
                int s = eidx[j];
                v8h val = *(const v8h*)(t2 + (size_t)s * K + c * 8);
#pragma unroll
                for (int q = 0; q < 8; ++q) acc[q] += (float)val[q];
            }
        }
        v8h o;
#pragma unroll
        for (int q = 0; q < 8; ++q)
            o[q] = (half_t)fmaxf((acc[q] * ii + b2[c * 8 + q]) * io, 0.f);
        *(v8h*)&As[r][c * 8] = o;
    }
    __syncthreads();

    {
        int mt = wave;
        v8h a[4];
#pragma unroll
        for (int kc = 0; kc < 4; ++kc)
            a[kc] = *(const v8h*)&As[mt * 16 + l16][kc * 32 + quad * 8];
        v4f acc[3] = {};
#pragma unroll
        for (int kc = 0; kc < 4; ++kc)
#pragma unroll
            for (int j = 0; j < 3; ++j)
                acc[j] = __builtin_amdgcn_mfma_f32_16x16x32_f16(a[kc], b[j][kc], acc[j], 0, 0, 0);
#pragma unroll
        for (int j = 0; j < 3; ++j) {
            int gn = j * 16 + l16;
            if (gn >= N) continue;
#pragma unroll
            for (int r = 0; r < 4; ++r) {
                int gm = m0 + mt * 16 + quad * 4 + r;
                if (gm < N_NODES) t3[(size_t)gm * N + gn] = (half_t)acc[j][r];
            }
        }
    }
}

// ---------------- final gather (fp16 rows, fp32 out) ----------------
// out[n,:] = segsum(t3)[n,:]*invIn[n] + b3

__global__ void gather_final(const half_t* __restrict__ x,
                             const int* __restrict__ rowptr, const int* __restrict__ eidx,
                             float* __restrict__ out, const float* __restrict__ invIn,
                             const float* __restrict__ bias) {
    constexpr int F = 40, V = 5;
    int t = blockIdx.x * blockDim.x + threadIdx.x;
    int n = t / V;
    int v = t - n * V;
    if (n >= N_NODES) return;
    int beg = rowptr[n], end = rowptr[n + 1];
    float acc[8] = {};
    for (int j = beg; j < end; ++j) {
        int s = eidx[j];
        v8h val = *(const v8h*)(x + (size_t)s * F + v * 8);
#pragma unroll
        for (int q = 0; q < 8; ++q) acc[q] += (float)val[q];
    }
    float ii = invIn[n];
    float* o = out + (size_t)n * F + v * 8;
#pragma unroll
    for (int q = 0; q < 8; ++q) o[q] = acc[q] * ii + bias[v * 8 + q];
}

// ---------------- launch ----------------

extern "C" void kernel_launch(void* const* d_in, const int* in_sizes, int n_in,
                              void* d_out, int out_size, void* d_ws, size_t ws_size,
                              hipStream_t stream) {
    const float* x  = (const float*)d_in[0];
    const int* src  = (const int*)d_in[1];
    const int* dst  = (const int*)d_in[2];
    const float* W1 = (const float*)d_in[3];
    const float* b1 = (const float*)d_in[4];
    const float* W2 = (const float*)d_in[5];
    const float* b2 = (const float*)d_in[6];
    const float* W3 = (const float*)d_in[7];
    const float* b3 = (const float*)d_in[8];
    float* out = (float*)d_out;
    const int E = in_sizes[1];

    char* ws = (char*)d_ws;
    int* ocnt     = (int*)ws;                     // 100000 (becomes inv_out f32)
    int* icnt     = (int*)(ws + 400000);          // 100000 (becomes inv_in f32)
    int* rowptr   = (int*)(ws + 800000);          // 100001
    int* cursor   = (int*)(ws + 1200256);         // 100000
    int* eidx     = (int*)(ws + 1600256);         // 800000 (3.2 MB)
    int* blockSum = (int*)(ws + 4800256);         // 128
    half_t* Wt1   = (half_t*)(ws + 4800768);      // 256x128 fp16 (64 KB)
    half_t* Wt2   = (half_t*)(ws + 4866304);      // 128x256 fp16 (64 KB)
    half_t* Wt3   = (half_t*)(ws + 4931840);      // 40x128 fp16 (10 KB)
    half_t* buf0  = (half_t*)(ws + 5000192);      // 25.6 MB: xh, later t3
    half_t* buf1  = (half_t*)(ws + 30600192);     // 25.6 MB: t2
    half_t* buf2  = (half_t*)(ws + 56200192);     // 51.2 MB: h1
    const float* inv_out = (const float*)ocnt;
    const float* inv_in  = (const float*)icnt;

    // ---- CSR + norms ----
    hipMemsetAsync(ocnt, 0, 800000, stream);
    count_kernel<<<(E + 255) / 256, 256, 0, stream>>>(src, dst, ocnt, icnt, E);
    scan_reduce<<<SCAN_NB, SCAN_TPB, 0, stream>>>(icnt, blockSum, N_NODES);
    scan_offsets<<<1, SCAN_NB, 0, stream>>>(blockSum, rowptr + N_NODES);
    scan_final<<<SCAN_NB, SCAN_TPB, 0, stream>>>(icnt, blockSum, rowptr, cursor, N_NODES);
    norm_kernel<<<(N_NODES + 255) / 256, 256, 0, stream>>>(ocnt, icnt, N_NODES);
    fill_kernel<<<(E + 255) / 256, 256, 0, stream>>>(src, dst, cursor, eidx, E);

    // ---- weight transpose+convert, x convert (x * inv_out -> fp16) ----
    convT_w<<<(128 * 256 + 255) / 256, 256, 0, stream>>>(W1, Wt1, 128, 256);
    convT_w<<<(256 * 128 + 255) / 256, 256, 0, stream>>>(W2, Wt2, 256, 128);
    convT_w<<<(128 * 40 + 255) / 256, 256, 0, stream>>>(W3, Wt3, 128, 40);
    conv_x<<<(N_NODES * 32 + 255) / 256, 256, 0, stream>>>(x, inv_out, buf0);

    const int NB = (N_NODES + 63) / 64;  // 1563

    // Layer 1 fused: h1 = relu((segsum(xh) @ W1)*inv_in + b1)*inv_out
    fused_l1<<<NB, 256, 0, stream>>>(buf0, rowptr, eidx, Wt1, inv_in, inv_out, b1, buf2);
    // Layer 2 transform: t2 = h1 @ W2
    gemm2_kernel<<<NB, 256, 0, stream>>>(buf2, Wt2, buf1);
    // Layer 3 fused: t3 = (relu((segsum(t2))*inv_in + b2)*inv_out) @ W3
    fused_l3<<<NB, 256, 0, stream>>>(buf1, rowptr, eidx, Wt3, inv_in, inv_out, b2, buf0);
    // Final gather: out = segsum(t3)*inv_in + b3
    gather_final<<<(N_NODES * 5 + 255) / 256, 256, 0, stream>>>(
        buf0, rowptr, eidx, out, inv_in, b3);
}

// Round 6
// 405.076 us; speedup vs baseline: 1.1005x; 1.1005x over previous
//
#include <hip/hip_runtime.h>

#define N_NODES 100000
#define SCAN_NB 128
#define SCAN_TPB 256

typedef _Float16 half_t;
typedef __attribute__((ext_vector_type(8))) _Float16 v8h;
typedef __attribute__((ext_vector_type(4))) _Float16 v4h;
typedef __attribute__((ext_vector_type(4))) float v4f;

// ---------------- CSR build ----------------

__global__ void count_kernel(const int* __restrict__ src, const int* __restrict__ dst,
                             int* __restrict__ ocnt, int* __restrict__ icnt, int E) {
    int e = blockIdx.x * blockDim.x + threadIdx.x;
    if (e < E) {
        atomicAdd(&ocnt[src[e]], 1);
        atomicAdd(&icnt[dst[e]], 1);
    }
}

__global__ __launch_bounds__(SCAN_TPB) void scan_reduce(const int* __restrict__ cnt,
                                                        int* __restrict__ blockSum, int n) {
    __shared__ int s[SCAN_TPB];
    int chunk = (n + SCAN_NB - 1) / SCAN_NB;
    int beg = blockIdx.x * chunk;
    int end = min(beg + chunk, n);
    int sum = 0;
    for (int i = beg + threadIdx.x; i < end; i += SCAN_TPB) sum += cnt[i];
    s[threadIdx.x] = sum;
    __syncthreads();
    for (int off = SCAN_TPB / 2; off > 0; off >>= 1) {
        if (threadIdx.x < off) s[threadIdx.x] += s[threadIdx.x + off];
        __syncthreads();
    }
    if (threadIdx.x == 0) blockSum[blockIdx.x] = s[0];
}

__global__ __launch_bounds__(SCAN_NB) void scan_offsets(int* __restrict__ blockSum,
                                                        int* __restrict__ rowptr_total) {
    __shared__ int s[SCAN_NB];
    int tid = threadIdx.x;
    int v = blockSum[tid];
    s[tid] = v;
    __syncthreads();
    for (int off = 1; off < SCAN_NB; off <<= 1) {
        int t = (tid >= off) ? s[tid - off] : 0;
        __syncthreads();
        s[tid] += t;
        __syncthreads();
    }
    blockSum[tid] = s[tid] - v;
    if (tid == SCAN_NB - 1) rowptr_total[0] = s[tid];
}

__global__ __launch_bounds__(SCAN_TPB) void scan_final(const int* __restrict__ cnt,
                                                       const int* __restrict__ blockSum,
                                                       int* __restrict__ rowptr,
                                                       int* __restrict__ cursor, int n) {
    __shared__ int s[SCAN_TPB];
    int chunk = (n + SCAN_NB - 1) / SCAN_NB;
    int beg = blockIdx.x * chunk;
    int end = min(beg + chunk, n);
    int carry = blockSum[blockIdx.x];
    for (int base = beg; base < end; base += SCAN_TPB) {
        int i = base + threadIdx.x;
        int v = (i < end) ? cnt[i] : 0;
        s[threadIdx.x] = v;
        __syncthreads();
        for (int off = 1; off < SCAN_TPB; off <<= 1) {
            int t = (threadIdx.x >= off) ? s[threadIdx.x - off] : 0;
            __syncthreads();
            s[threadIdx.x] += t;
            __syncthreads();
        }
        int excl = s[threadIdx.x] - v;
        if (i < end) {
            rowptr[i] = carry + excl;
            cursor[i] = carry + excl;
        }
        int roundSum = s[SCAN_TPB - 1];
        __syncthreads();
        carry += roundSum;
    }
}

__global__ void norm_kernel(int* __restrict__ ocnt, int* __restrict__ icnt, int n) {
    int i = blockIdx.x * blockDim.x + threadIdx.x;
    if (i < n) {
        float o = (float)max(ocnt[i], 1);
        float in = (float)max(icnt[i], 1);
        ((float*)ocnt)[i] = rsqrtf(o);
        ((float*)icnt)[i] = rsqrtf(in);
    }
}

__global__ void fill_kernel(const int* __restrict__ src, const int* __restrict__ dst,
                            int* __restrict__ cursor, int* __restrict__ eidx, int E) {
    int e = blockIdx.x * blockDim.x + threadIdx.x;
    if (e < E) {
        int pos = atomicAdd(&cursor[dst[e]], 1);
        eidx[pos] = src[e];
    }
}

// ---------------- conversions ----------------

__global__ void conv_x(const float* __restrict__ x, const float* __restrict__ invOut,
                       half_t* __restrict__ xh) {
    int t = blockIdx.x * blockDim.x + threadIdx.x;  // N_NODES*32 chunks
    int n = t >> 5;
    if (n >= N_NODES) return;
    float4 v = ((const float4*)x)[t];
    float s = invOut[n];
    v4h h;
    h[0] = (half_t)(v.x * s);
    h[1] = (half_t)(v.y * s);
    h[2] = (half_t)(v.z * s);
    h[3] = (half_t)(v.w * s);
    *(v4h*)(xh + (size_t)t * 4) = h;
}

// Wt[n][k] = (half) W[k][n]
__global__ void convT_w(const float* __restrict__ W, half_t* __restrict__ Wt, int K, int N) {
    int t = blockIdx.x * blockDim.x + threadIdx.x;
    if (t >= K * N) return;
    int n = t / K;
    int k = t - n * K;
    Wt[t] = (half_t)W[(size_t)k * N + n];
}

// 4-edge-unrolled CSR row segment-sum into fp32 acc[8].
// F = row stride in halves; c = chunk index (8 halves per chunk).
template <int F>
__device__ __forceinline__ void gather_row(const half_t* __restrict__ x,
                                           const int* __restrict__ eidx,
                                           int beg, int end, int c, float* acc) {
    int j = beg;
    int tail = beg + ((end - beg) & ~3);
    for (; j < tail; j += 4) {
        int s0 = eidx[j + 0], s1 = eidx[j + 1], s2 = eidx[j + 2], s3 = eidx[j + 3];
        v8h v0 = *(const v8h*)(x + (size_t)s0 * F + c * 8);
        v8h v1 = *(const v8h*)(x + (size_t)s1 * F + c * 8);
        v8h v2 = *(const v8h*)(x + (size_t)s2 * F + c * 8);
        v8h v3 = *(const v8h*)(x + (size_t)s3 * F + c * 8);
#pragma unroll
        for (int q = 0; q < 8; ++q)
            acc[q] += ((float)v0[q] + (float)v1[q]) + ((float)v2[q] + (float)v3[q]);
    }
    for (; j < end; ++j) {
        int s = eidx[j];
        v8h val = *(const v8h*)(x + (size_t)s * F + c * 8);
#pragma unroll
        for (int q = 0; q < 8; ++q) acc[q] += (float)val[q];
    }
}

// ---------------- fused gather + MFMA GEMM, layer 1 ----------------
// A-tile (64 rows) built by CSR gather of xh; C = relu((A@W1)*invIn + b1)*invOut, fp16.
// 4 waves, wave n-span 64 (N=256, 4 n-tiles/wave), B held in registers.

__global__ __launch_bounds__(256) void fused_l1(
    const half_t* __restrict__ xh, const int* __restrict__ rowptr,
    const int* __restrict__ eidx, const half_t* __restrict__ Wt1,
    const float* __restrict__ invIn, const float* __restrict__ invOut,
    const float* __restrict__ b1, half_t* __restrict__ h1) {
    constexpr int K = 128, N = 256, LDA = K + 8;  // 272B row: uniform 8 words/bank for b128
    __shared__ half_t As[64][LDA];
    __shared__ float iiS[64], ioS[64];
    const int tid = threadIdx.x;
    const int wave = tid >> 6, lane = tid & 63;
    const int quad = lane >> 4, l16 = lane & 15;
    const int m0 = blockIdx.x * 64;
    const int n0 = wave * 64;

    // B-fragments into registers (global loads overlap the gather phase)
    v8h b[4][4];
    float bv[4];
#pragma unroll
    for (int j = 0; j < 4; ++j) {
        int gn = n0 + j * 16 + l16;
        bv[j] = b1[gn];
#pragma unroll
        for (int kc = 0; kc < 4; ++kc)
            b[j][kc] = *(const v8h*)(Wt1 + (size_t)gn * K + kc * 32 + quad * 8);
    }
    if (tid < 64) {
        int gm = m0 + tid;
        bool ok = gm < N_NODES;
        iiS[tid] = ok ? invIn[gm] : 0.f;
        ioS[tid] = ok ? invOut[gm] : 0.f;
    }

    // gather phase: 64 rows x 16 chunks(8 halves) = 1024 tasks, 4 per thread.
#pragma unroll
    for (int t = 0; t < 4; ++t) {
        int task = tid + t * 256;
        int r = task >> 4, c = task & 15;
        int gm = m0 + r;
        float acc[8] = {};
        if (gm < N_NODES)
            gather_row<K>(xh, eidx, rowptr[gm], rowptr[gm + 1], c, acc);
        v8h o;
#pragma unroll
        for (int q = 0; q < 8; ++q) o[q] = (half_t)acc[q];
        *(v8h*)&As[r][c * 8] = o;
    }
    __syncthreads();

    // MFMA phase: 4 m-tiles per wave
    for (int mt = 0; mt < 4; ++mt) {
        v8h a[4];
#pragma unroll
        for (int kc = 0; kc < 4; ++kc)
            a[kc] = *(const v8h*)&As[mt * 16 + l16][kc * 32 + quad * 8];
        v4f acc[4] = {};
#pragma unroll
        for (int kc = 0; kc < 4; ++kc)
#pragma unroll
            for (int j = 0; j < 4; ++j)
                acc[j] = __builtin_amdgcn_mfma_f32_16x16x32_f16(a[kc], b[j][kc], acc[j], 0, 0, 0);
#pragma unroll
        for (int j = 0; j < 4; ++j) {
            int gn = n0 + j * 16 + l16;
#pragma unroll
            for (int r = 0; r < 4; ++r) {
                int lr = mt * 16 + quad * 4 + r;
                int gm = m0 + lr;
                if (gm < N_NODES) {
                    float z = (acc[j][r] * iiS[lr] + bv[j]) * ioS[lr];
                    h1[(size_t)gm * N + gn] = (half_t)fmaxf(z, 0.f);
                }
            }
        }
    }
}

// ---------------- GEMM2: t2 = h1 @ W2, single-stage A, B in regs ----------------
// M=1e5, K=256, N=128. 4 waves, wave n-span 32 (2 n-tiles).

__global__ __launch_bounds__(256) void gemm2_kernel(
    const half_t* __restrict__ A, const half_t* __restrict__ Wt2,
    half_t* __restrict__ C) {
    constexpr int K = 256, N = 128, LDA = K + 8;  // 528B row
    __shared__ half_t As[64][LDA];
    const int tid = threadIdx.x;
    const int wave = tid >> 6, lane = tid & 63;
    const int quad = lane >> 4, l16 = lane & 15;
    const int m0 = blockIdx.x * 64;
    const int n0 = wave * 32;

    v8h b[2][8];
#pragma unroll
    for (int j = 0; j < 2; ++j) {
        int gn = n0 + j * 16 + l16;
#pragma unroll
        for (int kc = 0; kc < 8; ++kc)
            b[j][kc] = *(const v8h*)(Wt2 + (size_t)gn * K + kc * 32 + quad * 8);
    }

    // stage A: 64 rows x 32 chunks(16B) = 2048 tasks, 8 per thread (coalesced rows)
#pragma unroll
    for (int t = 0; t < 8; ++t) {
        int task = tid + t * 256;
        int r = task >> 5, c = task & 31;
        int gm = m0 + r;
        float4 v = make_float4(0.f, 0.f, 0.f, 0.f);
        if (gm < N_NODES) v = *(const float4*)(A + (size_t)gm * K + c * 8);
        *(float4*)&As[r][c * 8] = v;
    }
    __syncthreads();

    for (int mt = 0; mt < 4; ++mt) {
        v8h a[8];
#pragma unroll
        for (int kc = 0; kc < 8; ++kc)
            a[kc] = *(const v8h*)&As[mt * 16 + l16][kc * 32 + quad * 8];
        v4f acc[2] = {};
#pragma unroll
        for (int kc = 0; kc < 8; ++kc)
#pragma unroll
            for (int j = 0; j < 2; ++j)
                acc[j] = __builtin_amdgcn_mfma_f32_16x16x32_f16(a[kc], b[j][kc], acc[j], 0, 0, 0);
#pragma unroll
        for (int j = 0; j < 2; ++j) {
            int gn = n0 + j * 16 + l16;
#pragma unroll
            for (int r = 0; r < 4; ++r) {
                int gm = m0 + mt * 16 + quad * 4 + r;
                if (gm < N_NODES) C[(size_t)gm * N + gn] = (half_t)acc[j][r];
            }
        }
    }
}

// ---------------- fused gather(+relu epi) + GEMM, layer 3 ----------------
// A-tile = h2 = relu((gather(t2))*invIn + b2)*invOut ; t3 = A @ W3 (N=40), fp16.

__global__ __launch_bounds__(256) void fused_l3(
    const half_t* __restrict__ t2, const int* __restrict__ rowptr,
    const int* __restrict__ eidx, const half_t* __restrict__ Wt3,
    const float* __restrict__ invIn, const float* __restrict__ invOut,
    const float* __restrict__ b2, half_t* __restrict__ t3) {
    constexpr int K = 128, N = 40, LDA = K + 8;
    __shared__ half_t As[64][LDA];
    const int tid = threadIdx.x;
    const int wave = tid >> 6, lane = tid & 63;
    const int quad = lane >> 4, l16 = lane & 15;
    const int m0 = blockIdx.x * 64;

    v8h b[3][4];
#pragma unroll
    for (int j = 0; j < 3; ++j) {
        int gn = j * 16 + l16;
#pragma unroll
        for (int kc = 0; kc < 4; ++kc)
            b[j][kc] = (gn < N) ? *(const v8h*)(Wt3 + (size_t)gn * K + kc * 32 + quad * 8)
                                : (v8h)(half_t)0;
    }

    // gather phase with fused relu epilogue
#pragma unroll
    for (int t = 0; t < 4; ++t) {
        int task = tid + t * 256;
        int r = task >> 4, c = task & 15;
        int gm = m0 + r;
        float acc[8] = {};
        float ii = 0.f, io = 0.f;
        if (gm < N_NODES) {
            ii = invIn[gm];
            io = invOut[gm];
            gather_row<K>(t2, eidx, rowptr[gm], rowptr[gm + 1], c, acc);
        }
        v8h o;
#pragma unroll
        for (int q = 0; q < 8; ++q)
            o[q] = (half_t)fmaxf((acc[q] * ii + b2[c * 8 + q]) * io, 0.f);
        *(v8h*)&As[r][c * 8] = o;
    }
    __syncthreads();

    {
        int mt = wave;
        v8h a[4];
#pragma unroll
        for (int kc = 0; kc < 4; ++kc)
            a[kc] = *(const v8h*)&As[mt * 16 + l16][kc * 32 + quad * 8];
        v4f acc[3] = {};
#pragma unroll
        for (int kc = 0; kc < 4; ++kc)
#pragma unroll
            for (int j = 0; j < 3; ++j)
                acc[j] = __builtin_amdgcn_mfma_f32_16x16x32_f16(a[kc], b[j][kc], acc[j], 0, 0, 0);
#pragma unroll
        for (int j = 0; j < 3; ++j) {
            int gn = j * 16 + l16;
            if (gn >= N) continue;
#pragma unroll
            for (int r = 0; r < 4; ++r) {
                int gm = m0 + mt * 16 + quad * 4 + r;
                if (gm < N_NODES) t3[(size_t)gm * N + gn] = (half_t)acc[j][r];
            }
        }
    }
}

// ---------------- final gather (fp16 rows, fp32 out) ----------------
// out[n,:] = segsum(t3)[n,:]*invIn[n] + b3

__global__ void gather_final(const half_t* __restrict__ x,
                             const int* __restrict__ rowptr, const int* __restrict__ eidx,
                             float* __restrict__ out, const float* __restrict__ invIn,
                             const float* __restrict__ bias) {
    constexpr int F = 40, V = 5;
    int t = blockIdx.x * blockDim.x + threadIdx.x;
    int n = t / V;
    int v = t - n * V;
    if (n >= N_NODES) return;
    float acc[8] = {};
    gather_row<F>(x, eidx, rowptr[n], rowptr[n + 1], v, acc);
    float ii = invIn[n];
    float* o = out + (size_t)n * F + v * 8;
#pragma unroll
    for (int q = 0; q < 8; ++q) o[q] = acc[q] * ii + bias[v * 8 + q];
}

// ---------------- launch ----------------

extern "C" void kernel_launch(void* const* d_in, const int* in_sizes, int n_in,
                              void* d_out, int out_size, void* d_ws, size_t ws_size,
                              hipStream_t stream) {
    const float* x  = (const float*)d_in[0];
    const int* src  = (const int*)d_in[1];
    const int* dst  = (const int*)d_in[2];
    const float* W1 = (const float*)d_in[3];
    const float* b1 = (const float*)d_in[4];
    const float* W2 = (const float*)d_in[5];
    const float* b2 = (const float*)d_in[6];
    const float* W3 = (const float*)d_in[7];
    const float* b3 = (const float*)d_in[8];
    float* out = (float*)d_out;
    const int E = in_sizes[1];

    char* ws = (char*)d_ws;
    int* ocnt     = (int*)ws;                     // 100000 (becomes inv_out f32)
    int* icnt     = (int*)(ws + 400000);          // 100000 (becomes inv_in f32)
    int* rowptr   = (int*)(ws + 800000);          // 100001
    int* cursor   = (int*)(ws + 1200256);         // 100000
    int* eidx     = (int*)(ws + 1600256);         // 800000 (3.2 MB)
    int* blockSum = (int*)(ws + 4800256);         // 128
    half_t* Wt1   = (half_t*)(ws + 4800768);      // 256x128 fp16 (64 KB)
    half_t* Wt2   = (half_t*)(ws + 4866304);      // 128x256 fp16 (64 KB)
    half_t* Wt3   = (half_t*)(ws + 4931840);      // 40x128 fp16 (10 KB)
    half_t* buf0  = (half_t*)(ws + 5000192);      // 25.6 MB: xh, later t3
    half_t* buf1  = (half_t*)(ws + 30600192);     // 25.6 MB: t2
    half_t* buf2  = (half_t*)(ws + 56200192);     // 51.2 MB: h1
    const float* inv_out = (const float*)ocnt;
    const float* inv_in  = (const float*)icnt;

    // ---- CSR + norms ----
    hipMemsetAsync(ocnt, 0, 800000, stream);
    count_kernel<<<(E + 255) / 256, 256, 0, stream>>>(src, dst, ocnt, icnt, E);
    scan_reduce<<<SCAN_NB, SCAN_TPB, 0, stream>>>(icnt, blockSum, N_NODES);
    scan_offsets<<<1, SCAN_NB, 0, stream>>>(blockSum, rowptr + N_NODES);
    scan_final<<<SCAN_NB, SCAN_TPB, 0, stream>>>(icnt, blockSum, rowptr, cursor, N_NODES);
    norm_kernel<<<(N_NODES + 255) / 256, 256, 0, stream>>>(ocnt, icnt, N_NODES);
    fill_kernel<<<(E + 255) / 256, 256, 0, stream>>>(src, dst, cursor, eidx, E);

    // ---- weight transpose+convert, x convert (x * inv_out -> fp16) ----
    convT_w<<<(128 * 256 + 255) / 256, 256, 0, stream>>>(W1, Wt1, 128, 256);
    convT_w<<<(256 * 128 + 255) / 256, 256, 0, stream>>>(W2, Wt2, 256, 128);
    convT_w<<<(128 * 40 + 255) / 256, 256, 0, stream>>>(W3, Wt3, 128, 40);
    conv_x<<<(N_NODES * 32 + 255) / 256, 256, 0, stream>>>(x, inv_out, buf0);

    const int NB = (N_NODES + 63) / 64;  // 1563

    // Layer 1 fused: h1 = relu((segsum(xh) @ W1)*inv_in + b1)*inv_out
    fused_l1<<<NB, 256, 0, stream>>>(buf0, rowptr, eidx, Wt1, inv_in, inv_out, b1, buf2);
    // Layer 2 transform: t2 = h1 @ W2
    gemm2_kernel<<<NB, 256, 0, stream>>>(buf2, Wt2, buf1);
    // Layer 3 fused: t3 = (relu((segsum(t2))*inv_in + b2)*inv_out) @ W3
    fused_l3<<<NB, 256, 0, stream>>>(buf1, rowptr, eidx, Wt3, inv_in, inv_out, b2, buf0);
    // Final gather: out = segsum(t3)*inv_in + b3
    gather_final<<<(N_NODES * 5 + 255) / 256, 256, 0, stream>>>(
        buf0, rowptr, eidx, out, inv_in, b3);
}

// Round 7
// 374.413 us; speedup vs baseline: 1.1906x; 1.0819x over previous
//
#include <hip/hip_runtime.h>

#define N_NODES 100000
#define SCAN_NB 128
#define SCAN_TPB 256

typedef _Float16 half_t;
typedef __attribute__((ext_vector_type(8))) _Float16 v8h;
typedef __attribute__((ext_vector_type(4))) _Float16 v4h;
typedef __attribute__((ext_vector_type(4))) float v4f;

// ---------------- CSR build ----------------

__global__ void count_kernel(const int* __restrict__ src, const int* __restrict__ dst,
                             int* __restrict__ ocnt, int* __restrict__ icnt, int E) {
    int e = blockIdx.x * blockDim.x + threadIdx.x;
    if (e < E) {
        atomicAdd(&ocnt[src[e]], 1);
        atomicAdd(&icnt[dst[e]], 1);
    }
}

__global__ __launch_bounds__(SCAN_TPB) void scan_reduce(const int* __restrict__ cnt,
                                                        int* __restrict__ blockSum, int n) {
    __shared__ int s[SCAN_TPB];
    int chunk = (n + SCAN_NB - 1) / SCAN_NB;
    int beg = blockIdx.x * chunk;
    int end = min(beg + chunk, n);
    int sum = 0;
    for (int i = beg + threadIdx.x; i < end; i += SCAN_TPB) sum += cnt[i];
    s[threadIdx.x] = sum;
    __syncthreads();
    for (int off = SCAN_TPB / 2; off > 0; off >>= 1) {
        if (threadIdx.x < off) s[threadIdx.x] += s[threadIdx.x + off];
        __syncthreads();
    }
    if (threadIdx.x == 0) blockSum[blockIdx.x] = s[0];
}

__global__ __launch_bounds__(SCAN_NB) void scan_offsets(int* __restrict__ blockSum,
                                                        int* __restrict__ rowptr_total) {
    __shared__ int s[SCAN_NB];
    int tid = threadIdx.x;
    int v = blockSum[tid];
    s[tid] = v;
    __syncthreads();
    for (int off = 1; off < SCAN_NB; off <<= 1) {
        int t = (tid >= off) ? s[tid - off] : 0;
        __syncthreads();
        s[tid] += t;
        __syncthreads();
    }
    blockSum[tid] = s[tid] - v;
    if (tid == SCAN_NB - 1) rowptr_total[0] = s[tid];
}

// Phase 3: in-chunk scan + block offset -> rowptr, cursor. Also converts
// ocnt/icnt (int degree) -> inv-sqrt norms (float, in place) — this is the
// last reader of the raw counts.
__global__ __launch_bounds__(SCAN_TPB) void scan_final(int* __restrict__ cnt,
                                                       int* __restrict__ ocnt,
                                                       const int* __restrict__ blockSum,
                                                       int* __restrict__ rowptr,
                                                       int* __restrict__ cursor, int n) {
    __shared__ int s[SCAN_TPB];
    int chunk = (n + SCAN_NB - 1) / SCAN_NB;
    int beg = blockIdx.x * chunk;
    int end = min(beg + chunk, n);
    int carry = blockSum[blockIdx.x];
    for (int base = beg; base < end; base += SCAN_TPB) {
        int i = base + threadIdx.x;
        int v = (i < end) ? cnt[i] : 0;
        s[threadIdx.x] = v;
        __syncthreads();
        for (int off = 1; off < SCAN_TPB; off <<= 1) {
            int t = (threadIdx.x >= off) ? s[threadIdx.x - off] : 0;
            __syncthreads();
            s[threadIdx.x] += t;
            __syncthreads();
        }
        int excl = s[threadIdx.x] - v;
        if (i < end) {
            rowptr[i] = carry + excl;
            cursor[i] = carry + excl;
            int o = ocnt[i];
            ((float*)ocnt)[i] = rsqrtf((float)max(o, 1));
            ((float*)cnt)[i] = rsqrtf((float)max(v, 1));
        }
        int roundSum = s[SCAN_TPB - 1];
        __syncthreads();
        carry += roundSum;
    }
}

__global__ void fill_kernel(const int* __restrict__ src, const int* __restrict__ dst,
                            int* __restrict__ cursor, int* __restrict__ eidx, int E) {
    int e = blockIdx.x * blockDim.x + threadIdx.x;
    if (e < E) {
        int pos = atomicAdd(&cursor[dst[e]], 1);
        eidx[pos] = src[e];
    }
}

// ---------------- conversions ----------------

__global__ void conv_x(const float* __restrict__ x, const float* __restrict__ invOut,
                       half_t* __restrict__ xh) {
    int t = blockIdx.x * blockDim.x + threadIdx.x;  // N_NODES*32 chunks
    int n = t >> 5;
    if (n >= N_NODES) return;
    float4 v = ((const float4*)x)[t];
    float s = invOut[n];
    v4h h;
    h[0] = (half_t)(v.x * s);
    h[1] = (half_t)(v.y * s);
    h[2] = (half_t)(v.z * s);
    h[3] = (half_t)(v.w * s);
    *(v4h*)(xh + (size_t)t * 4) = h;
}

// All three weight transposes in one launch: Wt[n][k] = (half) W[k][n]
__global__ void convT_all(const float* __restrict__ W1, const float* __restrict__ W2,
                          const float* __restrict__ W3, half_t* __restrict__ Wt1,
                          half_t* __restrict__ Wt2, half_t* __restrict__ Wt3) {
    int t = blockIdx.x * blockDim.x + threadIdx.x;
    if (t < 32768) {                      // W1: K=128, N=256
        int n = t >> 7, k = t & 127;
        Wt1[t] = (half_t)W1[(size_t)k * 256 + n];
    } else if (t < 65536) {               // W2: K=256, N=128
        int u = t - 32768;
        int n = u >> 8, k = u & 255;
        Wt2[u] = (half_t)W2[(size_t)k * 128 + n];
    } else if (t < 65536 + 5120) {        // W3: K=128, N=40
        int u = t - 65536;
        int n = u >> 7, k = u & 127;
        Wt3[u] = (half_t)W3[(size_t)k * 40 + n];
    }
}

// 4-edge-unrolled CSR row segment-sum into fp32 acc[8].
template <int F>
__device__ __forceinline__ void gather_row(const half_t* __restrict__ x,
                                           const int* __restrict__ eidx,
                                           int beg, int end, int c, float* acc) {
    int j = beg;
    int tail = beg + ((end - beg) & ~3);
    for (; j < tail; j += 4) {
        int s0 = eidx[j + 0], s1 = eidx[j + 1], s2 = eidx[j + 2], s3 = eidx[j + 3];
        v8h v0 = *(const v8h*)(x + (size_t)s0 * F + c * 8);
        v8h v1 = *(const v8h*)(x + (size_t)s1 * F + c * 8);
        v8h v2 = *(const v8h*)(x + (size_t)s2 * F + c * 8);
        v8h v3 = *(const v8h*)(x + (size_t)s3 * F + c * 8);
#pragma unroll
        for (int q = 0; q < 8; ++q)
            acc[q] += ((float)v0[q] + (float)v1[q]) + ((float)v2[q] + (float)v3[q]);
    }
    for (; j < end; ++j) {
        int s = eidx[j];
        v8h val = *(const v8h*)(x + (size_t)s * F + c * 8);
#pragma unroll
        for (int q = 0; q < 8; ++q) acc[q] += (float)val[q];
    }
}

// ---------------- fused gather + GEMM1 + GEMM2 (layers 1+2 transform) ----------
// A-tile (64 rows) = segsum(xh) built by CSR gather;
// h1 = relu((A@W1)*invIn + b1)*invOut  -> kept in LDS only;
// t2 = h1 @ W2 -> global (fp16). B1/B2 fragments live in registers.

__global__ __launch_bounds__(256) void fused_l12(
    const half_t* __restrict__ xh, const int* __restrict__ rowptr,
    const int* __restrict__ eidx, const half_t* __restrict__ Wt1,
    const half_t* __restrict__ Wt2,
    const float* __restrict__ invIn, const float* __restrict__ invOut,
    const float* __restrict__ b1, half_t* __restrict__ t2) {
    constexpr int K1 = 128, N1 = 256, K2 = 256, N2 = 128;
    constexpr int LDA = K1 + 8;   // 136 halves
    constexpr int LDH = K2 + 8;   // 264 halves
    __shared__ half_t As[64][LDA];     // 17408 B
    __shared__ half_t h1S[64][LDH];    // 33792 B
    __shared__ float iiS[64], ioS[64];
    const int tid = threadIdx.x;
    const int wave = tid >> 6, lane = tid & 63;
    const int quad = lane >> 4, l16 = lane & 15;
    const int m0 = blockIdx.x * 64;
    const int n0 = wave * 64;   // GEMM1 column span per wave

    // B1 fragments into registers (overlap with gather)
    v8h b[4][4];
    float bv[4];
#pragma unroll
    for (int j = 0; j < 4; ++j) {
        int gn = n0 + j * 16 + l16;
        bv[j] = b1[gn];
#pragma unroll
        for (int kc = 0; kc < 4; ++kc)
            b[j][kc] = *(const v8h*)(Wt1 + (size_t)gn * K1 + kc * 32 + quad * 8);
    }
    if (tid < 64) {
        int gm = m0 + tid;
        bool ok = gm < N_NODES;
        iiS[tid] = ok ? invIn[gm] : 0.f;
        ioS[tid] = ok ? invOut[gm] : 0.f;
    }

    // gather phase: 64 rows x 16 chunks = 1024 tasks, 4 per thread
#pragma unroll
    for (int t = 0; t < 4; ++t) {
        int task = tid + t * 256;
        int r = task >> 4, c = task & 15;
        int gm = m0 + r;
        float acc[8] = {};
        if (gm < N_NODES)
            gather_row<K1>(xh, eidx, rowptr[gm], rowptr[gm + 1], c, acc);
        v8h o;
#pragma unroll
        for (int q = 0; q < 8; ++q) o[q] = (half_t)acc[q];
        *(v8h*)&As[r][c * 8] = o;
    }
    __syncthreads();

    // GEMM1: each wave does 4 m-tiles x its 4 n-tiles; epilogue -> h1S (LDS)
    for (int mt = 0; mt < 4; ++mt) {
        v8h a[4];
#pragma unroll
        for (int kc = 0; kc < 4; ++kc)
            a[kc] = *(const v8h*)&As[mt * 16 + l16][kc * 32 + quad * 8];
        v4f acc[4] = {};
#pragma unroll
        for (int kc = 0; kc < 4; ++kc)
#pragma unroll
            for (int j = 0; j < 4; ++j)
                acc[j] = __builtin_amdgcn_mfma_f32_16x16x32_f16(a[kc], b[j][kc], acc[j], 0, 0, 0);
#pragma unroll
        for (int j = 0; j < 4; ++j) {
            int cn = n0 + j * 16 + l16;  // column within [0,256)
#pragma unroll
            for (int r = 0; r < 4; ++r) {
                int lr = mt * 16 + quad * 4 + r;
                float z = (acc[j][r] * iiS[lr] + bv[j]) * ioS[lr];
                h1S[lr][cn] = (half_t)fmaxf(z, 0.f);
            }
        }
    }

    // B2 fragments (global loads overlap other waves' GEMM1 work)
    v8h b2[2][8];
    const int n02 = wave * 32;  // GEMM2 column span per wave
#pragma unroll
    for (int j = 0; j < 2; ++j) {
        int gn = n02 + j * 16 + l16;
#pragma unroll
        for (int kc = 0; kc < 8; ++kc)
            b2[j][kc] = *(const v8h*)(Wt2 + (size_t)gn * K2 + kc * 32 + quad * 8);
    }
    __syncthreads();

    // GEMM2: t2 = h1S @ W2, K=256
    for (int mt = 0; mt < 4; ++mt) {
        v8h a2[8];
#pragma unroll
        for (int kc = 0; kc < 8; ++kc)
            a2[kc] = *(const v8h*)&h1S[mt * 16 + l16][kc * 32 + quad * 8];
        v4f acc2[2] = {};
#pragma unroll
        for (int kc = 0; kc < 8; ++kc)
#pragma unroll
            for (int j = 0; j < 2; ++j)
                acc2[j] = __builtin_amdgcn_mfma_f32_16x16x32_f16(a2[kc], b2[j][kc], acc2[j], 0, 0, 0);
#pragma unroll
        for (int j = 0; j < 2; ++j) {
            int gn = n02 + j * 16 + l16;
#pragma unroll
            for (int r = 0; r < 4; ++r) {
                int gm = m0 + mt * 16 + quad * 4 + r;
                if (gm < N_NODES) t2[(size_t)gm * N2 + gn] = (half_t)acc2[j][r];
            }
        }
    }
}

// ---------------- fused gather(+relu epi) + GEMM, layer 3 ----------------
// A-tile = h2 = relu((gather(t2))*invIn + b2)*invOut ; t3 = A @ W3 (N=40), fp16.

__global__ __launch_bounds__(256) void fused_l3(
    const half_t* __restrict__ t2, const int* __restrict__ rowptr,
    const int* __restrict__ eidx, const half_t* __restrict__ Wt3,
    const float* __restrict__ invIn, const float* __restrict__ invOut,
    const float* __restrict__ b2, half_t* __restrict__ t3) {
    constexpr int K = 128, N = 40, LDA = K + 8;
    __shared__ half_t As[64][LDA];
    const int tid = threadIdx.x;
    const int wave = tid >> 6, lane = tid & 63;
    const int quad = lane >> 4, l16 = lane & 15;
    const int m0 = blockIdx.x * 64;

    v8h b[3][4];
#pragma unroll
    for (int j = 0; j < 3; ++j) {
        int gn = j * 16 + l16;
#pragma unroll
        for (int kc = 0; kc < 4; ++kc)
            b[j][kc] = (gn < N) ? *(const v8h*)(Wt3 + (size_t)gn * K + kc * 32 + quad * 8)
                                : (v8h)(half_t)0;
    }

    // gather phase with fused relu epilogue
#pragma unroll
    for (int t = 0; t < 4; ++t) {
        int task = tid + t * 256;
        int r = task >> 4, c = task & 15;
        int gm = m0 + r;
        float acc[8] = {};
        float ii = 0.f, io = 0.f;
        if (gm < N_NODES) {
            ii = invIn[gm];
            io = invOut[gm];
            gather_row<K>(t2, eidx, rowptr[gm], rowptr[gm + 1], c, acc);
        }
        v8h o;
#pragma unroll
        for (int q = 0; q < 8; ++q)
            o[q] = (half_t)fmaxf((acc[q] * ii + b2[c * 8 + q]) * io, 0.f);
        *(v8h*)&As[r][c * 8] = o;
    }
    __syncthreads();

    {
        int mt = wave;
        v8h a[4];
#pragma unroll
        for (int kc = 0; kc < 4; ++kc)
            a[kc] = *(const v8h*)&As[mt * 16 + l16][kc * 32 + quad * 8];
        v4f acc[3] = {};
#pragma unroll
        for (int kc = 0; kc < 4; ++kc)
#pragma unroll
            for (int j = 0; j < 3; ++j)
                acc[j] = __builtin_amdgcn_mfma_f32_16x16x32_f16(a[kc], b[j][kc], acc[j], 0, 0, 0);
#pragma unroll
        for (int j = 0; j < 3; ++j) {
            int gn = j * 16 + l16;
            if (gn >= N) continue;
#pragma unroll
            for (int r = 0; r < 4; ++r) {
                int gm = m0 + mt * 16 + quad * 4 + r;
                if (gm < N_NODES) t3[(size_t)gm * N + gn] = (half_t)acc[j][r];
            }
        }
    }
}

// ---------------- final gather (fp16 rows, fp32 out) ----------------
// out[n,:] = segsum(t3)[n,:]*invIn[n] + b3

__global__ void gather_final(const half_t* __restrict__ x,
                             const int* __restrict__ rowptr, const int* __restrict__ eidx,
                             float* __restrict__ out, const float* __restrict__ invIn,
                             const float* __restrict__ bias) {
    constexpr int F = 40, V = 5;
    int t = blockIdx.x * blockDim.x + threadIdx.x;
    int n = t / V;
    int v = t - n * V;
    if (n >= N_NODES) return;
    float acc[8] = {};
    gather_row<F>(x, eidx, rowptr[n], rowptr[n + 1], v, acc);
    float ii = invIn[n];
    float* o = out + (size_t)n * F + v * 8;
#pragma unroll
    for (int q = 0; q < 8; ++q) o[q] = acc[q] * ii + bias[v * 8 + q];
}

// ---------------- launch ----------------

extern "C" void kernel_launch(void* const* d_in, const int* in_sizes, int n_in,
                              void* d_out, int out_size, void* d_ws, size_t ws_size,
                              hipStream_t stream) {
    const float* x  = (const float*)d_in[0];
    const int* src  = (const int*)d_in[1];
    const int* dst  = (const int*)d_in[2];
    const float* W1 = (const float*)d_in[3];
    const float* b1 = (const float*)d_in[4];
    const float* W2 = (const float*)d_in[5];
    const float* b2 = (const float*)d_in[6];
    const float* W3 = (const float*)d_in[7];
    const float* b3 = (const float*)d_in[8];
    float* out = (float*)d_out;
    const int E = in_sizes[1];

    char* ws = (char*)d_ws;
    int* ocnt     = (int*)ws;                     // 100000 (becomes inv_out f32)
    int* icnt     = (int*)(ws + 400000);          // 100000 (becomes inv_in f32)
    int* rowptr   = (int*)(ws + 800000);          // 100001
    int* cursor   = (int*)(ws + 1200256);         // 100000
    int* eidx     = (int*)(ws + 1600256);         // 800000 (3.2 MB)
    int* blockSum = (int*)(ws + 4800256);         // 128
    half_t* Wt1   = (half_t*)(ws + 4800768);      // 256x128 fp16 (64 KB)
    half_t* Wt2   = (half_t*)(ws + 4866304);      // 128x256 fp16 (64 KB)
    half_t* Wt3   = (half_t*)(ws + 4931840);      // 40x128 fp16 (10 KB)
    half_t* buf0  = (half_t*)(ws + 5000192);      // 25.6 MB: xh, later t3
    half_t* buf1  = (half_t*)(ws + 30600192);     // 25.6 MB: t2
    const float* inv_out = (const float*)ocnt;
    const float* inv_in  = (const float*)icnt;

    // ---- CSR + norms ----
    hipMemsetAsync(ocnt, 0, 800000, stream);
    count_kernel<<<(E + 255) / 256, 256, 0, stream>>>(src, dst, ocnt, icnt, E);
    scan_reduce<<<SCAN_NB, SCAN_TPB, 0, stream>>>(icnt, blockSum, N_NODES);
    scan_offsets<<<1, SCAN_NB, 0, stream>>>(blockSum, rowptr + N_NODES);
    scan_final<<<SCAN_NB, SCAN_TPB, 0, stream>>>(icnt, ocnt, blockSum, rowptr, cursor, N_NODES);
    fill_kernel<<<(E + 255) / 256, 256, 0, stream>>>(src, dst, cursor, eidx, E);

    // ---- weight transpose+convert (one launch), x convert ----
    convT_all<<<(70656 + 255) / 256, 256, 0, stream>>>(W1, W2, W3, Wt1, Wt2, Wt3);
    conv_x<<<(N_NODES * 32 + 255) / 256, 256, 0, stream>>>(x, inv_out, buf0);

    const int NB = (N_NODES + 63) / 64;  // 1563

    // Layers 1+2: t2 = (relu((segsum(xh)@W1)*inv_in + b1)*inv_out) @ W2
    fused_l12<<<NB, 256, 0, stream>>>(buf0, rowptr, eidx, Wt1, Wt2,
                                      inv_in, inv_out, b1, buf1);
    // Layer 3: t3 = (relu((segsum(t2))*inv_in + b2)*inv_out) @ W3
    fused_l3<<<NB, 256, 0, stream>>>(buf1, rowptr, eidx, Wt3, inv_in, inv_out, b2, buf0);
    // Final gather: out = segsum(t3)*inv_in + b3
    gather_final<<<(N_NODES * 5 + 255) / 256, 256, 0, stream>>>(
        buf0, rowptr, eidx, out, inv_in, b3);
}